// Round 2
// baseline (322.887 us; speedup 1.0000x reference)
//
#include <hip/hip_runtime.h>
#include <math.h>

// FrequencyAwareHierarchicalEmbedding, MI355X/gfx950 — round 2
//
// B*L = 409600, D = 128, H = 32.
// d_in: fine_ids i32, coarse_ids i32, fine_W[1000001*128] f32,
//       coarse_W[10001*128] f32, freq_W[1000001] f32, W1[257*32], b1[32],
//       W2[32], b2[1].
// d_out: fused[BL*128] f32, then adjusted_gate[BL] f32.
//
// 3-kernel plan:
//  A) coarse_mlp: hc[r][j] = b1[j] + coarse_row(r) @ W1[128..255]  (10001x32
//     into d_ws). 41 MFMA total — removes half the per-position MLP work and
//     the coarse scattered gather from the gate phase.
//  B) gate: one position per lane. Fine row streamed as double-buffered
//     float4x4 (loads issued 1024 fmac-cycles ahead); W1/W2/b2 wave-uniform
//     (scalar loads, co-issued on the scalar pipe). Writes adjusted_gate.
//  C) fuse: 32 lanes per position, float4 each — 1KB coalesced loads/stores.
//     Fine rows re-read through L3 (~172MB distinct, L3-resident).

#define DD 128
#define HH 32

__device__ __forceinline__ float sigmoid_f(float x) {
    return 1.0f / (1.0f + expf(-x));
}

// ---------------------------------------------------------------- kernel A --
__global__ __launch_bounds__(256) void coarse_mlp_kernel(
    const float* __restrict__ coarse_W,
    const float* __restrict__ W1,
    const float* __restrict__ b1,
    float* __restrict__ hc,
    int nCoarse)
{
    const int t = blockIdx.x * 256 + threadIdx.x;
    if (t >= nCoarse * HH) return;
    const int r = t >> 5;
    const int j = t & 31;
    const float* __restrict__ row = coarse_W + (size_t)r * DD;
    const float* __restrict__ w   = W1 + DD * HH + j;   // coarse rows of W1
    float acc = b1[j];
    #pragma unroll 8
    for (int i = 0; i < DD; ++i)
        acc = fmaf(row[i], w[i * HH], acc);
    hc[t] = acc;
}

// ---------------------------------------------------------------- kernel B --
__device__ __forceinline__ void acc4(float h[HH], const float* __restrict__ w,
                                     float4 v) {
    #pragma unroll
    for (int j = 0; j < HH; ++j) h[j] = fmaf(w[j], v.x, h[j]);
    #pragma unroll
    for (int j = 0; j < HH; ++j) h[j] = fmaf(w[HH + j], v.y, h[j]);
    #pragma unroll
    for (int j = 0; j < HH; ++j) h[j] = fmaf(w[2 * HH + j], v.z, h[j]);
    #pragma unroll
    for (int j = 0; j < HH; ++j) h[j] = fmaf(w[3 * HH + j], v.w, h[j]);
}

__global__ __launch_bounds__(256, 5) void gate_kernel(
    const int*   __restrict__ fine_ids,
    const int*   __restrict__ coarse_ids,
    const float* __restrict__ fine_W,
    const float* __restrict__ freq_W,
    const float* __restrict__ W1,
    const float* __restrict__ W2,
    const float* __restrict__ b2,
    const float* __restrict__ hc,
    float* __restrict__ out_gate)
{
    const int p = blockIdx.x * 256 + threadIdx.x;
    const int idf = fine_ids[p];
    const int idc = coarse_ids[p];

    const float4* __restrict__ rowf = (const float4*)(fine_W + (size_t)idf * DD);
    const float4* __restrict__ hcr  = (const float4*)(hc + idc * HH);

    // issue the first fine-row loads ASAP (HBM miss ~900cy)
    float4 a0 = rowf[0], a1 = rowf[1], a2 = rowf[2], a3 = rowf[3];

    const float fw = sigmoid_f(freq_W[idf]);

    float h[HH];
    #pragma unroll
    for (int g = 0; g < 8; ++g) {
        const float4 v = hcr[g];
        h[4 * g + 0] = v.x; h[4 * g + 1] = v.y;
        h[4 * g + 2] = v.z; h[4 * g + 3] = v.w;
    }

    // stream the fine row, 4 float4 in flight, 512 fmacs per group
    #pragma unroll
    for (int g = 0; g < 8; ++g) {
        float4 n0, n1, n2, n3;
        if (g < 7) {
            n0 = rowf[4 * g + 4]; n1 = rowf[4 * g + 5];
            n2 = rowf[4 * g + 6]; n3 = rowf[4 * g + 7];
        }
        const float* __restrict__ w = W1 + (size_t)g * 16 * HH; // uniform
        acc4(h, w,           a0);
        acc4(h, w +  4 * HH, a1);
        acc4(h, w +  8 * HH, a2);
        acc4(h, w + 12 * HH, a3);
        a0 = n0; a1 = n1; a2 = n2; a3 = n3;
    }

    // freq feature (W1 row 256)
    {
        const float* __restrict__ w = W1 + 2 * DD * HH;
        #pragma unroll
        for (int j = 0; j < HH; ++j) h[j] = fmaf(w[j], fw, h[j]);
    }

    float s = b2[0];
    #pragma unroll
    for (int j = 0; j < HH; ++j) s = fmaf(fmaxf(h[j], 0.0f), W2[j], s);

    out_gate[p] = sigmoid_f(s) * fw;     // coalesced
}

// ---------------------------------------------------------------- kernel C --
__global__ __launch_bounds__(256) void fuse_kernel(
    const int*   __restrict__ fine_ids,
    const int*   __restrict__ coarse_ids,
    const float* __restrict__ fine_W,
    const float* __restrict__ coarse_W,
    const float* __restrict__ adj_g,
    float* __restrict__ out_fused)
{
    const int t   = blockIdx.x * 256 + threadIdx.x;
    const int pos = t >> 5;
    const int d0  = (t & 31) * 4;

    const float a  = adj_g[pos];
    const int  idf = fine_ids[pos];
    const int  idc = coarse_ids[pos];

    const float4 f = *(const float4*)(fine_W   + (size_t)idf * DD + d0);
    const float4 c = *(const float4*)(coarse_W + (size_t)idc * DD + d0);

    float4 o;
    o.x = fmaf(a, f.x - c.x, c.x);
    o.y = fmaf(a, f.y - c.y, c.y);
    o.z = fmaf(a, f.z - c.z, c.z);
    o.w = fmaf(a, f.w - c.w, c.w);

    *(float4*)(out_fused + (size_t)pos * DD + d0) = o;   // 1KB/instr coalesced
}

// ------------------------------------------------------------------- launch --
extern "C" void kernel_launch(void* const* d_in, const int* in_sizes, int n_in,
                              void* d_out, int out_size, void* d_ws, size_t ws_size,
                              hipStream_t stream) {
    const int*   fine_ids   = (const int*)  d_in[0];
    const int*   coarse_ids = (const int*)  d_in[1];
    const float* fine_W     = (const float*)d_in[2];
    const float* coarse_W   = (const float*)d_in[3];
    const float* freq_W     = (const float*)d_in[4];
    const float* W1         = (const float*)d_in[5];
    const float* b1         = (const float*)d_in[6];
    const float* W2         = (const float*)d_in[7];
    const float* b2         = (const float*)d_in[8];

    const int n       = in_sizes[0];          // B*L = 409600 (divisible by 256)
    const int nCoarse = in_sizes[3] / DD;     // 10001

    float* out_fused = (float*)d_out;
    float* out_gate  = (float*)d_out + (size_t)n * DD;
    float* hc        = (float*)d_ws;          // nCoarse*32 floats = 1.28 MB

    coarse_mlp_kernel<<<dim3((nCoarse * HH + 255) / 256), dim3(256), 0, stream>>>(
        coarse_W, W1, b1, hc, nCoarse);

    gate_kernel<<<dim3(n / 256), dim3(256), 0, stream>>>(
        fine_ids, coarse_ids, fine_W, freq_W, W1, W2, b2, hc, out_gate);

    fuse_kernel<<<dim3(n / 8), dim3(256), 0, stream>>>(
        fine_ids, coarse_ids, fine_W, coarse_W, out_gate, out_fused);
}

// Round 3
// 186.653 us; speedup vs baseline: 1.7299x; 1.7299x over previous
//
#include <hip/hip_runtime.h>
#include <math.h>

// FrequencyAwareHierarchicalEmbedding, MI355X/gfx950 — round 3
//
// B*L = 409600, D = 128, H = 32.
// d_in: fine_ids i32, coarse_ids i32, fine_W[1000001*128] f32,
//       coarse_W[10001*128] f32, freq_W[1000001] f32, W1[257*32], b1[32],
//       W2[32], b2[1].
// d_out: fused[BL*128] f32, then adjusted_gate[BL] f32.
//
// Structure (round-1 fused shape + two fixes):
//  A) hc precompute: hc[r][j] = b1[j] + coarse_row(r) @ W1[128..255]
//     (10001 x 32 into d_ws, ~4us). Halves per-position MLP FLOPs and removes
//     the coarse scattered gather from the gate phase.
//  B) fused kernel:
//     Phase 1 (position-per-lane): h init from hc[idc] (L2-resident),
//       fine row streamed as float4 with one-group-ahead prefetch; W1 fine
//       half (16KB) staged in LDS, weights read as wave-uniform ds_read_b128
//       (broadcast, conflict-free) into VGPRs -> every MAC is one v_fmac_f32.
//       No scalar-cache dependence.
//     Phase 2 (wave-cooperative, same kernel for L1/L2 locality): 2 positions
//       per iteration, float4 per lane -> 1KB coalesced loads/stores.

#define DD 128
#define HH 32

__device__ __forceinline__ float sigmoid_f(float x) {
    return 1.0f / (1.0f + expf(-x));
}

// ---------------------------------------------------------------- kernel A --
__global__ __launch_bounds__(256) void coarse_mlp_kernel(
    const float* __restrict__ coarse_W,
    const float* __restrict__ W1,
    const float* __restrict__ b1,
    float* __restrict__ hc,
    int nCoarse)
{
    const int t = blockIdx.x * 256 + threadIdx.x;
    if (t >= nCoarse * HH) return;
    const int r = t >> 5;
    const int j = t & 31;
    const float* __restrict__ row = coarse_W + (size_t)r * DD;
    const float* __restrict__ w   = W1 + DD * HH + j;   // coarse rows of W1
    float acc = b1[j];
    #pragma unroll 8
    for (int i = 0; i < DD; ++i)
        acc = fmaf(row[i], w[i * HH], acc);
    hc[t] = acc;
}

// ---------------------------------------------------------------- kernel B --
// one input element i: 8 uniform LDS float4 weight reads + 32 fmacs
#define ACC_I(xval, ibase)                                                   \
    {                                                                        \
        const float4* __restrict__ wr = (const float4*)(sW1 + (ibase));      \
        _Pragma("unroll")                                                    \
        for (int r = 0; r < 8; ++r) {                                        \
            const float4 w = wr[r];                                          \
            h[4 * r + 0] = fmaf(w.x, (xval), h[4 * r + 0]);                  \
            h[4 * r + 1] = fmaf(w.y, (xval), h[4 * r + 1]);                  \
            h[4 * r + 2] = fmaf(w.z, (xval), h[4 * r + 2]);                  \
            h[4 * r + 3] = fmaf(w.w, (xval), h[4 * r + 3]);                  \
        }                                                                    \
    }

__global__ __launch_bounds__(256, 4) void fused_kernel(
    const int*   __restrict__ fine_ids,
    const int*   __restrict__ coarse_ids,
    const float* __restrict__ fine_W,
    const float* __restrict__ coarse_W,
    const float* __restrict__ freq_W,
    const float* __restrict__ W1,
    const float* __restrict__ W2,
    const float* __restrict__ b2,
    const float* __restrict__ hc,
    float* __restrict__ out_fused,
    float* __restrict__ out_gate)
{
    __shared__ float sW1[DD * HH];      // fine half of W1: 16 KB
    __shared__ float s_adj[256];
    __shared__ int   s_if[256];
    __shared__ int   s_ic[256];

    const int tid  = threadIdx.x;
    const int lane = tid & 63;
    const int wave = tid >> 6;
    const int blockStart = (int)blockIdx.x * 256;
    const int p = blockStart + tid;

    // ---- stage fine half of W1 into LDS (4096 floats, 4 float4/thread) ----
    {
        const float4* __restrict__ w4 = (const float4*)W1;
        float4* s4 = (float4*)sW1;
        #pragma unroll
        for (int k = 0; k < 4; ++k)
            s4[tid + 256 * k] = w4[tid + 256 * k];
    }

    // ---- per-lane gathers issued early --------------------------------
    const int idf = fine_ids[p];
    const int idc = coarse_ids[p];
    const float4* __restrict__ rowf = (const float4*)(fine_W + (size_t)idf * DD);

    float4 xc[4], xn[4];
    #pragma unroll
    for (int k = 0; k < 4; ++k) xc[k] = rowf[k];
    const float fraw = freq_W[idf];

    float h[HH];
    {
        const float4* __restrict__ hc4 = (const float4*)(hc + idc * HH);
        #pragma unroll
        for (int g = 0; g < 8; ++g) {
            const float4 v = hc4[g];
            h[4 * g + 0] = v.x; h[4 * g + 1] = v.y;
            h[4 * g + 2] = v.z; h[4 * g + 3] = v.w;
        }
    }
    const float fw = sigmoid_f(fraw);

    __syncthreads();    // sW1 ready

    // ---- phase 1: fine_emb @ W1[0..127] -------------------------------
    #pragma unroll 1
    for (int g = 0; g < 8; ++g) {
        if (g < 7) {
            #pragma unroll
            for (int k = 0; k < 4; ++k) xn[k] = rowf[4 * g + 4 + k];
        }
        #pragma unroll
        for (int q = 0; q < 4; ++q) {
            const int ib = (g * 16 + q * 4) * HH;
            ACC_I(xc[q].x, ib);
            ACC_I(xc[q].y, ib + HH);
            ACC_I(xc[q].z, ib + 2 * HH);
            ACC_I(xc[q].w, ib + 3 * HH);
        }
        #pragma unroll
        for (int k = 0; k < 4; ++k) xc[k] = xn[k];
    }

    // freq feature (W1 row 256) — single row, wave-uniform scalar loads fine
    {
        const float* __restrict__ w = W1 + 2 * DD * HH;
        #pragma unroll
        for (int j = 0; j < HH; ++j) h[j] = fmaf(w[j], fw, h[j]);
    }

    // gate = sigmoid(relu(h) @ W2 + b2); adjusted = gate * fw
    float s = b2[0];
    #pragma unroll
    for (int j = 0; j < HH; ++j) s = fmaf(fmaxf(h[j], 0.0f), W2[j], s);
    const float adj = sigmoid_f(s) * fw;

    out_gate[p] = adj;                  // coalesced
    s_adj[tid] = adj;
    s_if[tid]  = idf;
    s_ic[tid]  = idc;
    __syncthreads();

    // ---- phase 2: fusion, wave-cooperative, float4, 2 positions/iter ----
    const int half = lane >> 5;         // 0/1: which position of the pair
    const int d0   = (lane & 31) * 4;   // 32 lanes cover the 128-float row
    const int waveBase = wave * 64;
    #pragma unroll 1
    for (int q = 0; q < 64; q += 2) {
        const int slot = waveBase + q + half;
        const float a  = s_adj[slot];                 // LDS broadcast (2 addrs)
        const int   jf = s_if[slot] * DD;
        const int   jc = s_ic[slot] * DD;
        const float4 f = *(const float4*)(fine_W   + jf + d0);   // L1/L2 hit
        const float4 c = *(const float4*)(coarse_W + jc + d0);   // L2-resident
        float4 o;
        o.x = fmaf(a, f.x - c.x, c.x);
        o.y = fmaf(a, f.y - c.y, c.y);
        o.z = fmaf(a, f.z - c.z, c.z);
        o.w = fmaf(a, f.w - c.w, c.w);
        *(float4*)(out_fused + (size_t)(blockStart + slot) * DD + d0) = o;
    }
}

// ------------------------------------------------------------------- launch --
extern "C" void kernel_launch(void* const* d_in, const int* in_sizes, int n_in,
                              void* d_out, int out_size, void* d_ws, size_t ws_size,
                              hipStream_t stream) {
    const int*   fine_ids   = (const int*)  d_in[0];
    const int*   coarse_ids = (const int*)  d_in[1];
    const float* fine_W     = (const float*)d_in[2];
    const float* coarse_W   = (const float*)d_in[3];
    const float* freq_W     = (const float*)d_in[4];
    const float* W1         = (const float*)d_in[5];
    const float* b1         = (const float*)d_in[6];
    const float* W2         = (const float*)d_in[7];
    const float* b2         = (const float*)d_in[8];

    const int n       = in_sizes[0];          // B*L = 409600 (divisible by 256)
    const int nCoarse = in_sizes[3] / DD;     // 10001

    float* out_fused = (float*)d_out;
    float* out_gate  = (float*)d_out + (size_t)n * DD;
    float* hc        = (float*)d_ws;          // nCoarse*32 floats = 1.28 MB

    coarse_mlp_kernel<<<dim3((nCoarse * HH + 255) / 256), dim3(256), 0, stream>>>(
        coarse_W, W1, b1, hc, nCoarse);

    fused_kernel<<<dim3(n / 256), dim3(256), 0, stream>>>(
        fine_ids, coarse_ids, fine_W, coarse_W, freq_W,
        W1, W2, b2, hc, out_fused, out_gate);
}

// Round 5
// 169.622 us; speedup vs baseline: 1.9036x; 1.1004x over previous
//
#include <hip/hip_runtime.h>
#include <math.h>

// FrequencyAwareHierarchicalEmbedding, MI355X/gfx950 — round 5 (r4 + compile fix)
//
// B*L = 409600, D = 128, H = 32.
// d_in: fine_ids i32, coarse_ids i32, fine_W[1000001*128] f32,
//       coarse_W[10001*128] f32, freq_W[1000001] f32, W1[257*32], b1[32],
//       W2[32], b2[1].
// d_out: fused[BL*128] f32, then adjusted_gate[BL] f32.
//
// Changes vs round 3 (187us):
//  * Weights via SCALAR path (K$), not LDS: wave-uniform s_loads, one load
//    serves 64 positions. Fine half of W1 = 16KB, K$-resident.
//  * g-loop not unrolled -> small I$ footprint.
//  * Nontemporal stores for the 210MB output stream (don't evict gathered
//    fine rows from L2/L3 before the phase-2 re-read).
//  * hc precompute retained (coarse half of MLP folded per coarse-row).
//  * Fix vs round 4: nontemporal store uses a native ext_vector_type float4.

#define DD 128
#define HH 32

typedef float f32x4 __attribute__((ext_vector_type(4)));

__device__ __forceinline__ float sigmoid_f(float x) {
    return 1.0f / (1.0f + expf(-x));
}

// ---------------------------------------------------------------- kernel A --
__global__ __launch_bounds__(256) void coarse_mlp_kernel(
    const float* __restrict__ coarse_W,
    const float* __restrict__ W1,
    const float* __restrict__ b1,
    float* __restrict__ hc,
    int nCoarse)
{
    const int t = blockIdx.x * 256 + threadIdx.x;
    if (t >= nCoarse * HH) return;
    const int r = t >> 5;
    const int j = t & 31;
    const float* __restrict__ row = coarse_W + (size_t)r * DD;
    const float* __restrict__ w   = W1 + DD * HH + j;   // coarse rows of W1
    float acc = b1[j];
    #pragma unroll 8
    for (int i = 0; i < DD; ++i)
        acc = fmaf(row[i], w[i * HH], acc);
    hc[t] = acc;
}

// ---------------------------------------------------------------- kernel B --
__device__ __forceinline__ void acc4(float h[HH], const float* __restrict__ w,
                                     float4 v) {
    #pragma unroll
    for (int j = 0; j < HH; ++j) h[j] = fmaf(w[j], v.x, h[j]);
    #pragma unroll
    for (int j = 0; j < HH; ++j) h[j] = fmaf(w[HH + j], v.y, h[j]);
    #pragma unroll
    for (int j = 0; j < HH; ++j) h[j] = fmaf(w[2 * HH + j], v.z, h[j]);
    #pragma unroll
    for (int j = 0; j < HH; ++j) h[j] = fmaf(w[3 * HH + j], v.w, h[j]);
}

__global__ __launch_bounds__(256, 5) void fused_kernel(
    const int*   __restrict__ fine_ids,
    const int*   __restrict__ coarse_ids,
    const float* __restrict__ fine_W,
    const float* __restrict__ coarse_W,
    const float* __restrict__ freq_W,
    const float* __restrict__ W1,
    const float* __restrict__ W2,
    const float* __restrict__ b2,
    const float* __restrict__ hc,
    float* __restrict__ out_fused,
    float* __restrict__ out_gate)
{
    __shared__ float s_adj[256];
    __shared__ int   s_if[256];
    __shared__ int   s_ic[256];

    const int tid  = threadIdx.x;
    const int lane = tid & 63;
    const int wave = tid >> 6;
    const int blockStart = (int)blockIdx.x * 256;
    const int p = blockStart + tid;

    // ---- per-lane gathers issued early --------------------------------
    const int idf = fine_ids[p];
    const int idc = coarse_ids[p];
    const float4* __restrict__ rowf = (const float4*)(fine_W + (size_t)idf * DD);

    float4 xc0 = rowf[0], xc1 = rowf[1], xc2 = rowf[2], xc3 = rowf[3];
    const float fraw = freq_W[idf];

    float h[HH];
    {
        const float4* __restrict__ hc4 = (const float4*)(hc + idc * HH);
        #pragma unroll
        for (int g = 0; g < 8; ++g) {
            const float4 v = hc4[g];
            h[4 * g + 0] = v.x; h[4 * g + 1] = v.y;
            h[4 * g + 2] = v.z; h[4 * g + 3] = v.w;
        }
    }
    const float fw = sigmoid_f(fraw);

    // ---- phase 1: fine_emb @ W1[0..127], weights via K$ ----------------
    #pragma unroll 1
    for (int g = 0; g < 8; ++g) {
        float4 xn0, xn1, xn2, xn3;
        if (g < 7) {
            xn0 = rowf[4 * g + 4]; xn1 = rowf[4 * g + 5];
            xn2 = rowf[4 * g + 6]; xn3 = rowf[4 * g + 7];
        }
        const float* __restrict__ w = W1 + g * 16 * HH;   // wave-uniform
        acc4(h, w,           xc0);
        acc4(h, w +  4 * HH, xc1);
        acc4(h, w +  8 * HH, xc2);
        acc4(h, w + 12 * HH, xc3);
        xc0 = xn0; xc1 = xn1; xc2 = xn2; xc3 = xn3;
    }

    // freq feature (W1 row 256) — wave-uniform
    {
        const float* __restrict__ w = W1 + 2 * DD * HH;
        #pragma unroll
        for (int j = 0; j < HH; ++j) h[j] = fmaf(w[j], fw, h[j]);
    }

    // gate = sigmoid(relu(h) @ W2 + b2); adjusted = gate * fw
    float s = b2[0];
    #pragma unroll
    for (int j = 0; j < HH; ++j) s = fmaf(fmaxf(h[j], 0.0f), W2[j], s);
    const float adj = sigmoid_f(s) * fw;

    __builtin_nontemporal_store(adj, out_gate + p);   // coalesced, write-only
    s_adj[tid] = adj;
    s_if[tid]  = idf;
    s_ic[tid]  = idc;
    __syncthreads();

    // ---- phase 2: fusion, wave-cooperative, float4, 2 positions/iter ----
    const int half = lane >> 5;         // 0/1: which position of the pair
    const int d0   = (lane & 31) * 4;   // 32 lanes cover the 128-float row
    const int waveBase = wave * 64;
    #pragma unroll 1
    for (int q = 0; q < 64; q += 2) {
        const int slot = waveBase + q + half;
        const float a  = s_adj[slot];                 // LDS broadcast (2 addrs)
        const int   jf = s_if[slot] * DD;
        const int   jc = s_ic[slot] * DD;
        const float4 f = *(const float4*)(fine_W   + jf + d0);   // L1/L2 hit
        const float4 c = *(const float4*)(coarse_W + jc + d0);   // L2-resident
        f32x4 o;
        o.x = fmaf(a, f.x - c.x, c.x);
        o.y = fmaf(a, f.y - c.y, c.y);
        o.z = fmaf(a, f.z - c.z, c.z);
        o.w = fmaf(a, f.w - c.w, c.w);
        f32x4* dst = (f32x4*)(out_fused + (size_t)(blockStart + slot) * DD + d0);
        __builtin_nontemporal_store(o, dst);          // never re-read
    }
}

// ------------------------------------------------------------------- launch --
extern "C" void kernel_launch(void* const* d_in, const int* in_sizes, int n_in,
                              void* d_out, int out_size, void* d_ws, size_t ws_size,
                              hipStream_t stream) {
    const int*   fine_ids   = (const int*)  d_in[0];
    const int*   coarse_ids = (const int*)  d_in[1];
    const float* fine_W     = (const float*)d_in[2];
    const float* coarse_W   = (const float*)d_in[3];
    const float* freq_W     = (const float*)d_in[4];
    const float* W1         = (const float*)d_in[5];
    const float* b1         = (const float*)d_in[6];
    const float* W2         = (const float*)d_in[7];
    const float* b2         = (const float*)d_in[8];

    const int n       = in_sizes[0];          // B*L = 409600 (divisible by 256)
    const int nCoarse = in_sizes[3] / DD;     // 10001

    float* out_fused = (float*)d_out;
    float* out_gate  = (float*)d_out + (size_t)n * DD;
    float* hc        = (float*)d_ws;          // nCoarse*32 floats = 1.28 MB

    coarse_mlp_kernel<<<dim3((nCoarse * HH + 255) / 256), dim3(256), 0, stream>>>(
        coarse_W, W1, b1, hc, nCoarse);

    fused_kernel<<<dim3(n / 256), dim3(256), 0, stream>>>(
        fine_ids, coarse_ids, fine_W, coarse_W, freq_W,
        W1, W2, b2, hc, out_fused, out_gate);
}